// Round 4
// baseline (200.044 us; speedup 1.0000x reference)
//
#include <hip/hip_runtime.h>
#include <stdint.h>

// graphConv: out[b] = (sum_k W_k S^k) @ X_b ; B=128, N=1024, D=64, K=8
//
// All-fp16 tree (fp32 MFMA accumulate), 5 launches:
//   prep: cvt S (rm+cm), W1,W3,W5,W7 (rm) -> fp16 + transpose X -> XT
//   L1: S2 = S*S (rm+cm) ; U_j = W_{2j}(fp32 acc-preload) + W_{2j+1}*S
//   L2: S4 = S2*S2 (cm) ; V0 = U0 + U1*S2 ; V1 = U2 + U3*S2
//   L3: A = V0(fp16 acc-preload) + V1*S4
//   apply: out = A @ X as ONE 1024 x 8192 x 1024 GEMM
//
// R4 change: tree GEMMs (gemm_v2) read the A-operand DIRECTLY from global
// (L2-resident) into per-lane register fragments -- waves stacked in M so
// each wave owns its A rows. Only B is LDS-staged (16 KB dbuf). This
// halves the LDS-read:MFMA ratio to 0.5 (m97-class) WITHOUT the 64KB-LDS
// occupancy cliff that killed the 128^2-tile attempt (R1). A-frag loads
// for step kk+1 issue before the MFMAs of kk; the end-of-step barrier's
// vmcnt(0) drain guarantees arrival. 2-phase dbuf, one barrier/K-step,
// XOR-swizzled B rows (conflict-free), global_load_lds w=16.

#define NN 1024
#define NBATCH 128
#define DDIM 64

typedef float floatx4 __attribute__((ext_vector_type(4)));
typedef _Float16 f16x8 __attribute__((ext_vector_type(8)));
typedef unsigned short u16;

__device__ __forceinline__ u16 f2h(float f) {
  union { _Float16 h; u16 u; } v; v.h = (_Float16)f; return v.u;
}
__device__ __forceinline__ float h2f(u16 u) {
  union { _Float16 h; u16 u; } v; v.u = u; return (float)v.h;
}

__device__ __forceinline__ void gll16(const void* g, void* l) {
  __builtin_amdgcn_global_load_lds(
      (const __attribute__((address_space(1))) void*)g,
      (__attribute__((address_space(3))) void*)l, 16, 0, 0);
}

// Stage ROWS x 64 u16 tile (row stride NN) into linear LDS, 16B chunks
// XOR-swizzled by row&7. Conflict-free on DMA write and ds_read_b128.
template <int ROWS>
__device__ __forceinline__ void stage64(const u16* __restrict__ g, u16* lds,
                                        int wave, int lane) {
  const int r = lane >> 3, c = lane & 7;
  const int sw = (c ^ r) * 8;
#pragma unroll
  for (int i = 0; i < ROWS / 32; ++i) {
    const int rb = wave * (ROWS / 4) + i * 8;
    gll16(g + (size_t)(rb + r) * NN + sw, lds + rb * 64);
  }
}

// ---------------- prep: cvt fp32->fp16 (5 jobs) + transpose X --------------
struct CvtJob { const float* src; u16* rm; u16* cm; };
struct CvtJobs { CvtJob j[5]; };

// blocks [0,5120): cvt (job = bid>>10); blocks [5120,7168): transpose X.
__global__ __launch_bounds__(256) void prep_kernel(CvtJobs jobs,
                                                   const float* __restrict__ X,
                                                   u16* __restrict__ XT) {
  __shared__ u16 T[64][72];
  const int bid = blockIdx.x;
  const int t = threadIdx.x;
  if (bid < 5120) {
    CvtJob jb = jobs.j[bid >> 10];
    int idx4 = (bid & 1023) * 256 + t;
    int e = idx4 * 4;
    int row = e >> 10, col = e & (NN - 1);
    float4 f = ((const float4*)jb.src)[idx4];
    u16 h[4] = { f2h(f.x), f2h(f.y), f2h(f.z), f2h(f.w) };
    uint2 p;
    p.x = (uint32_t)h[0] | ((uint32_t)h[1] << 16);
    p.y = (uint32_t)h[2] | ((uint32_t)h[3] << 16);
    *(uint2*)&jb.rm[e] = p;
    if (jb.cm) {
#pragma unroll
      for (int i = 0; i < 4; ++i) jb.cm[(size_t)(col + i) * NN + row] = h[i];
    }
  } else {
    const int tb = bid - 5120;
    const int k0 = (tb & 15) * 64;
    const int b = tb >> 4;
#pragma unroll
    for (int it = 0; it < 4; ++it) {
      int kr = (t >> 4) + it * 16;
      int d4 = (t & 15) * 4;
      float4 f = *(const float4*)&X[((size_t)b * NN + k0 + kr) * DDIM + d4];
      T[d4 + 0][kr] = f2h(f.x);
      T[d4 + 1][kr] = f2h(f.y);
      T[d4 + 2][kr] = f2h(f.z);
      T[d4 + 3][kr] = f2h(f.w);
    }
    __syncthreads();
#pragma unroll
    for (int it = 0; it < 2; ++it) {
      int d = (t >> 3) + it * 32;
      int kc = (t & 7) * 8;
      *(uint4*)&XT[((size_t)b * DDIM + d) * NN + k0 + kc] = *(uint4*)&T[d][kc];
    }
  }
}

// ---------------- tree GEMM v2: A from global regs, B via LDS --------------
struct GemmJob {
  const u16* A;        // fp16 row-major MxK (L2/L3-resident)
  const u16* B;        // fp16 col-major: (k,n) at [n*NN+k]
  const float* addF;   // optional fp32 additive (row-major, acc-preloaded)
  const u16* addH;     // optional fp16 additive (row-major, acc-preloaded)
  u16* outRm;          // optional fp16 row-major out
  u16* outCm;          // optional fp16 col-major out
};
struct GemmJobs { GemmJob j[5]; };

// BM x 64 tile, 4 waves stacked in M (wave tile = BM/4 x 64, MI = BM/64).
// Per wave per K-step: MI*2 global dwordx4 (A frags) + 8 ds_read_b128 (B)
// feeding MI*8 MFMAs. LDS = 2 x 8 KB only.
template <int BM>
__global__ __launch_bounds__(256) void gemm_v2(GemmJobs jobs) {
  const GemmJob jb = jobs.j[blockIdx.z];
  __shared__ u16 Bs[2][64 * 64];
  const int t = threadIdx.x, wave = t >> 6, lane = t & 63;
  const int lm = lane & 15, q = lane >> 4;
  const int bm = blockIdx.x * BM, bn = blockIdx.y * 64;
  constexpr int MI = BM / 64;
  floatx4 acc[MI][4] = {};

  const u16* Bg = jb.B + (size_t)bn * NN;
  // per-lane A base: row = bm + wave*(BM/4) + lm, k-chunk = q*8
  const u16* Ap = jb.A + ((size_t)bm + wave * (BM / 4) + lm) * NN + q * 8;

  // Preload additive operand into acc fragments (latency hides under K-loop)
  if (jb.addF) {
#pragma unroll
    for (int mi = 0; mi < MI; ++mi)
#pragma unroll
      for (int ni = 0; ni < 4; ++ni)
#pragma unroll
        for (int r = 0; r < 4; ++r) {
          int row = bm + wave * (BM / 4) + mi * 16 + q * 4 + r;
          int col = bn + ni * 16 + lm;
          acc[mi][ni][r] = jb.addF[(size_t)row * NN + col];
        }
  } else if (jb.addH) {
#pragma unroll
    for (int mi = 0; mi < MI; ++mi)
#pragma unroll
      for (int ni = 0; ni < 4; ++ni)
#pragma unroll
        for (int r = 0; r < 4; ++r) {
          int row = bm + wave * (BM / 4) + mi * 16 + q * 4 + r;
          int col = bn + ni * 16 + lm;
          acc[mi][ni][r] = h2f(jb.addH[(size_t)row * NN + col]);
        }
  }

  f16x8 aF[2][MI * 2];
  stage64<64>(Bg, Bs[0], wave, lane);
#pragma unroll
  for (int mi = 0; mi < MI; ++mi)
#pragma unroll
    for (int ks = 0; ks < 2; ++ks)
      aF[0][mi * 2 + ks] =
          *(const f16x8*)(Ap + (size_t)mi * 16 * NN + ks * 32);
  __syncthreads();

#pragma unroll
  for (int kk = 0; kk < 16; ++kk) {
    const int cur = kk & 1;
    if (kk + 1 < 16) {  // prefetch next K-slab (B->LDS, A->regs)
      stage64<64>(Bg + (kk + 1) * 64, Bs[cur ^ 1], wave, lane);
#pragma unroll
      for (int mi = 0; mi < MI; ++mi)
#pragma unroll
        for (int ks = 0; ks < 2; ++ks)
          aF[cur ^ 1][mi * 2 + ks] = *(const f16x8*)(
              Ap + (size_t)mi * 16 * NN + (kk + 1) * 64 + ks * 32);
    }
#pragma unroll
    for (int ks = 0; ks < 2; ++ks) {
      const int st = ((ks * 4 + q) ^ (lm & 7)) * 8;
      f16x8 bf[4];
#pragma unroll
      for (int ni = 0; ni < 4; ++ni)
        bf[ni] = *(const f16x8*)&Bs[cur][(ni * 16 + lm) * 64 + st];
#pragma unroll
      for (int mi = 0; mi < MI; ++mi)
#pragma unroll
        for (int ni = 0; ni < 4; ++ni)
          acc[mi][ni] = __builtin_amdgcn_mfma_f32_16x16x32_f16(
              aF[cur][mi * 2 + ks], bf[ni], acc[mi][ni], 0, 0, 0);
    }
    __syncthreads();  // drains prefetch DMA + A-frag loads + read completion
  }

#pragma unroll
  for (int mi = 0; mi < MI; ++mi)
#pragma unroll
    for (int ni = 0; ni < 4; ++ni)
#pragma unroll
      for (int r = 0; r < 4; ++r) {
        int row = bm + wave * (BM / 4) + mi * 16 + q * 4 + r;
        int col = bn + ni * 16 + lm;
        size_t rm = (size_t)row * NN + col;
        u16 h = f2h(acc[mi][ni][r]);
        if (jb.outRm) jb.outRm[rm] = h;
        if (jb.outCm) jb.outCm[(size_t)col * NN + row] = h;
      }
}

// ---------------- apply: one 1024 x 8192 x 1024 GEMM -----------------------
// cols c = b*64 + d ; XT[c][k] is exactly the col-major B operand.
// 128x128 tiles, 4 waves of 64x64 (MI=NI=4), 2-phase dbuf.
// grid(x=coltile 64, y=rowtile 8): XCD = x%8 -> per XCD: 8 XT coltiles
// (2 MB) + full A (2 MB) L2-resident; 512 blocks = exactly 2/CU.
__global__ __launch_bounds__(256) void apply_gemm(const u16* __restrict__ A,
                                                  const u16* __restrict__ XT,
                                                  float* __restrict__ out) {
  __shared__ u16 As[2][128 * 64], Xs[2][128 * 64];  // 64 KB
  const int t = threadIdx.x, wave = t >> 6, lane = t & 63;
  const int wm = wave >> 1, wn = wave & 1;
  const int lm = lane & 15, q = lane >> 4;
  const int bn = blockIdx.x * 128;  // column tile (b*64+d)
  const int bm = blockIdx.y * 128;  // A row tile
  floatx4 acc[4][4] = {};
  const u16* Ag = A + (size_t)bm * NN;
  const u16* Xg = XT + (size_t)bn * NN;

  stage64<128>(Ag, As[0], wave, lane);
  stage64<128>(Xg, Xs[0], wave, lane);
  __syncthreads();

  for (int kt = 0; kt < 16; ++kt) {
    const int cur = kt & 1;
    if (kt + 1 < 16) {
      stage64<128>(Ag + (kt + 1) * 64, As[cur ^ 1], wave, lane);
      stage64<128>(Xg + (kt + 1) * 64, Xs[cur ^ 1], wave, lane);
    }
#pragma unroll
    for (int ks = 0; ks < 2; ++ks) {
      const int st = ((ks * 4 + q) ^ (lm & 7)) * 8;
      f16x8 xf[4];
#pragma unroll
      for (int ni = 0; ni < 4; ++ni)
        xf[ni] = *(const f16x8*)&Xs[cur][(wn * 64 + ni * 16 + lm) * 64 + st];
#pragma unroll
      for (int mi = 0; mi < 4; ++mi) {
        f16x8 a = *(const f16x8*)&As[cur][(wm * 64 + mi * 16 + lm) * 64 + st];
#pragma unroll
        for (int ni = 0; ni < 4; ++ni)
          acc[mi][ni] = __builtin_amdgcn_mfma_f32_16x16x32_f16(a, xf[ni], acc[mi][ni], 0, 0, 0);
      }
    }
    __syncthreads();
  }

#pragma unroll
  for (int mi = 0; mi < 4; ++mi)
#pragma unroll
    for (int ni = 0; ni < 4; ++ni)
#pragma unroll
      for (int r = 0; r < 4; ++r) {
        int row = bm + wm * 64 + mi * 16 + q * 4 + r;
        int col = bn + wn * 64 + ni * 16 + lm;  // = b*64 + d
        out[((size_t)(col >> 6) * NN + row) * DDIM + (col & 63)] =
            acc[mi][ni][r];
      }
}

extern "C" void kernel_launch(void* const* d_in, const int* in_sizes, int n_in,
                              void* d_out, int out_size, void* d_ws, size_t ws_size,
                              hipStream_t stream) {
  const float* nodes  = (const float*)d_in[0];  // [128,1024,64]
  const float* weight = (const float*)d_in[1];  // [8,1024,1024]
  const float* gs     = (const float*)d_in[2];  // [1024,1024]
  float* out = (float*)d_out;
  u16* ws = (u16*)d_ws;
  const size_t MB = (size_t)NN * NN;
  auto buf = [&](int i) -> u16* { return ws + (size_t)i * MB; };
  // 2MB fp16 slots: 0 S rm | 1 S cm | 2..5 W1,3,5,7 rm | 6 S2 rm | 7 S2 cm
  // 8..11 U0..U3 | 12 S4 cm | 13 V0 | 14 V1 | 15 A | 16..23 XT (16 MB)

  u16* XT = buf(16);
  CvtJobs cv{};
  cv.j[0] = { gs,              buf(0), buf(1) };
  cv.j[1] = { weight + 1 * MB, buf(2), nullptr };
  cv.j[2] = { weight + 3 * MB, buf(3), nullptr };
  cv.j[3] = { weight + 5 * MB, buf(4), nullptr };
  cv.j[4] = { weight + 7 * MB, buf(5), nullptr };
  prep_kernel<<<dim3(5120 + 2048), 256, 0, stream>>>(cv, nodes, XT);

  // L1: S2 = S*S ; U_j = W_{2j}(acc-preload) + W_{2j+1}*S
  // 128x64 tiles, grid 640 = 2.5 blocks/CU, LDS 16KB, A global-direct
  GemmJobs g1{};
  g1.j[0] = { buf(0), buf(1), nullptr,         nullptr, buf(6),  buf(7)  };
  g1.j[1] = { buf(2), buf(1), weight + 0 * MB, nullptr, buf(8),  nullptr };
  g1.j[2] = { buf(3), buf(1), weight + 2 * MB, nullptr, buf(9),  nullptr };
  g1.j[3] = { buf(4), buf(1), weight + 4 * MB, nullptr, buf(10), nullptr };
  g1.j[4] = { buf(5), buf(1), weight + 6 * MB, nullptr, buf(11), nullptr };
  gemm_v2<128><<<dim3(8, 16, 5), 256, 0, stream>>>(g1);

  // L2: S4 = S2*S2 (cm) ; V0 = U0 + U1*S2 ; V1 = U2 + U3*S2
  // 64x64 tiles, grid 768 = 3 blocks/CU
  GemmJobs g2{};
  g2.j[0] = { buf(6),  buf(7), nullptr, nullptr, nullptr, buf(12) };
  g2.j[1] = { buf(9),  buf(7), nullptr, buf(8),  buf(13), nullptr };
  g2.j[2] = { buf(11), buf(7), nullptr, buf(10), buf(14), nullptr };
  gemm_v2<64><<<dim3(16, 16, 3), 256, 0, stream>>>(g2);

  // L3: A = V0(fp16 acc-preload) + V1*S4 -- direct write
  GemmJobs g3{};
  g3.j[0] = { buf(14), buf(12), nullptr, buf(13), buf(15), nullptr };
  gemm_v2<64><<<dim3(16, 16, 1), 256, 0, stream>>>(g3);

  apply_gemm<<<dim3(64, 8), 256, 0, stream>>>(buf(15), XT, out);
}

// Round 5
// 186.902 us; speedup vs baseline: 1.0703x; 1.0703x over previous
//
#include <hip/hip_runtime.h>
#include <stdint.h>

// graphConv: out[b] = (sum_k W_k S^k) @ X_b ; B=128, N=1024, D=64, K=8
//
// All-fp16 tree (fp32 MFMA accumulate), 5 launches:
//   prep: cvt S (rm+cm), W1,W3,W5,W7 (rm) -> fp16 + transpose X -> XT
//   L1: S2 = S*S (rm+cm) ; U_j = W_{2j}(fp32 acc-preload) + W_{2j+1}*S
//   L2: S4 = S2*S2 (cm) ; V0 = U0 + U1*S2 ; V1 = U2 + U3*S2
//   L3: A = V0(fp16 acc-preload) + V1*S4
//   apply: out = A @ X as ONE 1024 x 8192 x 1024 GEMM
//
// R5 change: COUNTED-vmcnt pipeline (T3/T4) in every GEMM. The old
// __syncthreads() per K-step drains vmcnt(0) -- killing the prefetch
// every iteration (m97's known ~20%+ structural stall). Now:
//   stage(k+1) -> s_waitcnt vmcnt(N) [waits ONLY tile k's loads; k+1's
//   stay in flight] -> raw s_barrier -> ds_read+MFMA -> lgkmcnt(0) ->
//   raw s_barrier [reads complete before buf k is overwritten].
// N = loads/wave/K-step: L1=6, L2/L3=4, apply=8. Raw s_barrier (not
// __syncthreads) so the compiler does not re-insert the vmcnt(0) drain
// (m201-verified plain-HIP pattern). Geometry identical to R3.

#define NN 1024
#define NBATCH 128
#define DDIM 64

typedef float floatx4 __attribute__((ext_vector_type(4)));
typedef _Float16 f16x8 __attribute__((ext_vector_type(8)));
typedef unsigned short u16;

__device__ __forceinline__ u16 f2h(float f) {
  union { _Float16 h; u16 u; } v; v.h = (_Float16)f; return v.u;
}
__device__ __forceinline__ float h2f(u16 u) {
  union { _Float16 h; u16 u; } v; v.u = u; return (float)v.h;
}

__device__ __forceinline__ void gll16(const void* g, void* l) {
  __builtin_amdgcn_global_load_lds(
      (const __attribute__((address_space(1))) void*)g,
      (__attribute__((address_space(3))) void*)l, 16, 0, 0);
}

// Wait until at most N VMEM ops outstanding, then barrier. Counted N>0
// keeps the just-issued prefetch in flight across the barrier (T4).
template <int N>
__device__ __forceinline__ void wait_vm_barrier() {
  static_assert(N == 0 || N == 4 || N == 6 || N == 8, "literal table");
  if constexpr (N == 0) asm volatile("s_waitcnt vmcnt(0)" ::: "memory");
  else if constexpr (N == 4) asm volatile("s_waitcnt vmcnt(4)" ::: "memory");
  else if constexpr (N == 6) asm volatile("s_waitcnt vmcnt(6)" ::: "memory");
  else if constexpr (N == 8) asm volatile("s_waitcnt vmcnt(8)" ::: "memory");
  asm volatile("s_barrier" ::: "memory");
}

// All LDS reads data-complete, then barrier: the buffer we just consumed
// may now be overwritten by the next stage's DMA.
__device__ __forceinline__ void wait_lgkm_barrier() {
  asm volatile("s_waitcnt lgkmcnt(0)" ::: "memory");
  asm volatile("s_barrier" ::: "memory");
}

// Stage ROWS x 64 u16 tile (row stride NN) into linear LDS, 16B chunks
// XOR-swizzled by row&7. Conflict-free on DMA write and ds_read_b128.
// Issues ROWS/32 global_load_lds per wave.
template <int ROWS>
__device__ __forceinline__ void stage64(const u16* __restrict__ g, u16* lds,
                                        int wave, int lane) {
  const int r = lane >> 3, c = lane & 7;
  const int sw = (c ^ r) * 8;
#pragma unroll
  for (int i = 0; i < ROWS / 32; ++i) {
    const int rb = wave * (ROWS / 4) + i * 8;
    gll16(g + (size_t)(rb + r) * NN + sw, lds + rb * 64);
  }
}

// ---------------- prep: cvt fp32->fp16 (5 jobs) + transpose X --------------
struct CvtJob { const float* src; u16* rm; u16* cm; };
struct CvtJobs { CvtJob j[5]; };

// blocks [0,5120): cvt (job = bid>>10); blocks [5120,7168): transpose X.
__global__ __launch_bounds__(256) void prep_kernel(CvtJobs jobs,
                                                   const float* __restrict__ X,
                                                   u16* __restrict__ XT) {
  __shared__ u16 T[64][72];
  const int bid = blockIdx.x;
  const int t = threadIdx.x;
  if (bid < 5120) {
    CvtJob jb = jobs.j[bid >> 10];
    int idx4 = (bid & 1023) * 256 + t;
    int e = idx4 * 4;
    int row = e >> 10, col = e & (NN - 1);
    float4 f = ((const float4*)jb.src)[idx4];
    u16 h[4] = { f2h(f.x), f2h(f.y), f2h(f.z), f2h(f.w) };
    uint2 p;
    p.x = (uint32_t)h[0] | ((uint32_t)h[1] << 16);
    p.y = (uint32_t)h[2] | ((uint32_t)h[3] << 16);
    *(uint2*)&jb.rm[e] = p;
    if (jb.cm) {
#pragma unroll
      for (int i = 0; i < 4; ++i) jb.cm[(size_t)(col + i) * NN + row] = h[i];
    }
  } else {
    const int tb = bid - 5120;
    const int k0 = (tb & 15) * 64;
    const int b = tb >> 4;
#pragma unroll
    for (int it = 0; it < 4; ++it) {
      int kr = (t >> 4) + it * 16;
      int d4 = (t & 15) * 4;
      float4 f = *(const float4*)&X[((size_t)b * NN + k0 + kr) * DDIM + d4];
      T[d4 + 0][kr] = f2h(f.x);
      T[d4 + 1][kr] = f2h(f.y);
      T[d4 + 2][kr] = f2h(f.z);
      T[d4 + 3][kr] = f2h(f.w);
    }
    __syncthreads();
#pragma unroll
    for (int it = 0; it < 2; ++it) {
      int d = (t >> 3) + it * 32;
      int kc = (t & 7) * 8;
      *(uint4*)&XT[((size_t)b * DDIM + d) * NN + k0 + kc] = *(uint4*)&T[d][kc];
    }
  }
}

// ---------------- fp16 GEMM: out = [add +] A*B ----------------------------
struct GemmJob {
  const u16* A;        // fp16 row-major MxK
  const u16* B;        // fp16 col-major: (k,n) at [n*NN+k]
  const float* addF;   // optional fp32 additive (row-major, acc-preloaded)
  const u16* addH;     // optional fp16 additive (row-major, acc-preloaded)
  u16* outRm;          // optional fp16 row-major out
  u16* outCm;          // optional fp16 col-major out
};
struct GemmJobs { GemmJob j[5]; };

template <int BM, int BN, int WM, int WN>
__global__ __launch_bounds__(256) void gemm_f16(GemmJobs jobs) {
  const GemmJob jb = jobs.j[blockIdx.z];
  __shared__ u16 As[2][BM * 64], Bs[2][BN * 64];
  const int t = threadIdx.x, wave = t >> 6, lane = t & 63;
  const int wm = wave / WN, wn = wave % WN;
  const int lm = lane & 15, q = lane >> 4;
  const int bm = blockIdx.x * BM, bn = blockIdx.y * BN;
  constexpr int MI = BM / (WM * 16), NI = BN / (WN * 16);
  constexpr int VMC = (BM + BN) / 32;  // stage loads per wave per K-step
  floatx4 acc[MI][NI] = {};

  const u16* Ag = jb.A + (size_t)bm * NN;
  const u16* Bg = jb.B + (size_t)bn * NN;

  // Preload additive operand into acc fragments (latency hides under K-loop)
  if (jb.addF) {
#pragma unroll
    for (int mi = 0; mi < MI; ++mi)
#pragma unroll
      for (int ni = 0; ni < NI; ++ni)
#pragma unroll
        for (int r = 0; r < 4; ++r) {
          int row = bm + wm * (BM / WM) + mi * 16 + q * 4 + r;
          int col = bn + wn * (BN / WN) + ni * 16 + lm;
          acc[mi][ni][r] = jb.addF[(size_t)row * NN + col];
        }
  } else if (jb.addH) {
#pragma unroll
    for (int mi = 0; mi < MI; ++mi)
#pragma unroll
      for (int ni = 0; ni < NI; ++ni)
#pragma unroll
        for (int r = 0; r < 4; ++r) {
          int row = bm + wm * (BM / WM) + mi * 16 + q * 4 + r;
          int col = bn + wn * (BN / WN) + ni * 16 + lm;
          acc[mi][ni][r] = h2f(jb.addH[(size_t)row * NN + col]);
        }
  }

  stage64<BM>(Ag, As[0], wave, lane);
  stage64<BN>(Bg, Bs[0], wave, lane);

  for (int kk = 0; kk < 16; ++kk) {
    const int cur = kk & 1;
    if (kk + 1 < 16) {  // prefetch next K-slab into the other buffer
      stage64<BM>(Ag + (kk + 1) * 64, As[cur ^ 1], wave, lane);
      stage64<BN>(Bg + (kk + 1) * 64, Bs[cur ^ 1], wave, lane);
      wait_vm_barrier<VMC>();  // tile kk landed; kk+1 stays in flight
    } else {
      wait_vm_barrier<0>();
    }
#pragma unroll
    for (int ks = 0; ks < 2; ++ks) {
      const int st = ((ks * 4 + q) ^ (lm & 7)) * 8;
      f16x8 bf[NI];
#pragma unroll
      for (int ni = 0; ni < NI; ++ni)
        bf[ni] = *(const f16x8*)&Bs[cur][(wn * (BN / WN) + ni * 16 + lm) * 64 + st];
#pragma unroll
      for (int mi = 0; mi < MI; ++mi) {
        f16x8 a = *(const f16x8*)&As[cur][(wm * (BM / WM) + mi * 16 + lm) * 64 + st];
#pragma unroll
        for (int ni = 0; ni < NI; ++ni)
          acc[mi][ni] = __builtin_amdgcn_mfma_f32_16x16x32_f16(a, bf[ni], acc[mi][ni], 0, 0, 0);
      }
    }
    wait_lgkm_barrier();  // reads done; buf[cur] may be overwritten next
  }

#pragma unroll
  for (int mi = 0; mi < MI; ++mi)
#pragma unroll
    for (int ni = 0; ni < NI; ++ni)
#pragma unroll
      for (int r = 0; r < 4; ++r) {
        int row = bm + wm * (BM / WM) + mi * 16 + q * 4 + r;
        int col = bn + wn * (BN / WN) + ni * 16 + lm;
        size_t rm = (size_t)row * NN + col;
        u16 h = f2h(acc[mi][ni][r]);
        if (jb.outRm) jb.outRm[rm] = h;
        if (jb.outCm) jb.outCm[(size_t)col * NN + row] = h;
      }
}

// ---------------- apply: one 1024 x 8192 x 1024 GEMM -----------------------
// cols c = b*64 + d ; XT[c][k] is exactly the col-major B operand.
// 128x128 tiles, 4 waves of 64x64 (MI=NI=4), counted-vmcnt dbuf.
// grid(x=coltile 64, y=rowtile 8): XCD = x%8 -> per XCD: 8 XT coltiles
// (2 MB) + full A (2 MB) L2-resident; 512 blocks = exactly 2/CU.
__global__ __launch_bounds__(256) void apply_gemm(const u16* __restrict__ A,
                                                  const u16* __restrict__ XT,
                                                  float* __restrict__ out) {
  __shared__ u16 As[2][128 * 64], Xs[2][128 * 64];  // 64 KB
  const int t = threadIdx.x, wave = t >> 6, lane = t & 63;
  const int wm = wave >> 1, wn = wave & 1;
  const int lm = lane & 15, q = lane >> 4;
  const int bn = blockIdx.x * 128;  // column tile (b*64+d)
  const int bm = blockIdx.y * 128;  // A row tile
  floatx4 acc[4][4] = {};
  const u16* Ag = A + (size_t)bm * NN;
  const u16* Xg = XT + (size_t)bn * NN;

  stage64<128>(Ag, As[0], wave, lane);
  stage64<128>(Xg, Xs[0], wave, lane);

  for (int kt = 0; kt < 16; ++kt) {
    const int cur = kt & 1;
    if (kt + 1 < 16) {
      stage64<128>(Ag + (kt + 1) * 64, As[cur ^ 1], wave, lane);
      stage64<128>(Xg + (kt + 1) * 64, Xs[cur ^ 1], wave, lane);
      wait_vm_barrier<8>();  // tile kt landed; kt+1's 8 loads in flight
    } else {
      wait_vm_barrier<0>();
    }
#pragma unroll
    for (int ks = 0; ks < 2; ++ks) {
      const int st = ((ks * 4 + q) ^ (lm & 7)) * 8;
      f16x8 xf[4];
#pragma unroll
      for (int ni = 0; ni < 4; ++ni)
        xf[ni] = *(const f16x8*)&Xs[cur][(wn * 64 + ni * 16 + lm) * 64 + st];
#pragma unroll
      for (int mi = 0; mi < 4; ++mi) {
        f16x8 a = *(const f16x8*)&As[cur][(wm * 64 + mi * 16 + lm) * 64 + st];
#pragma unroll
        for (int ni = 0; ni < 4; ++ni)
          acc[mi][ni] = __builtin_amdgcn_mfma_f32_16x16x32_f16(a, xf[ni], acc[mi][ni], 0, 0, 0);
      }
    }
    wait_lgkm_barrier();
  }

#pragma unroll
  for (int mi = 0; mi < 4; ++mi)
#pragma unroll
    for (int ni = 0; ni < 4; ++ni)
#pragma unroll
      for (int r = 0; r < 4; ++r) {
        int row = bm + wm * 64 + mi * 16 + q * 4 + r;
        int col = bn + wn * 64 + ni * 16 + lm;  // = b*64 + d
        out[((size_t)(col >> 6) * NN + row) * DDIM + (col & 63)] =
            acc[mi][ni][r];
      }
}

extern "C" void kernel_launch(void* const* d_in, const int* in_sizes, int n_in,
                              void* d_out, int out_size, void* d_ws, size_t ws_size,
                              hipStream_t stream) {
  const float* nodes  = (const float*)d_in[0];  // [128,1024,64]
  const float* weight = (const float*)d_in[1];  // [8,1024,1024]
  const float* gs     = (const float*)d_in[2];  // [1024,1024]
  float* out = (float*)d_out;
  u16* ws = (u16*)d_ws;
  const size_t MB = (size_t)NN * NN;
  auto buf = [&](int i) -> u16* { return ws + (size_t)i * MB; };
  // 2MB fp16 slots: 0 S rm | 1 S cm | 2..5 W1,3,5,7 rm | 6 S2 rm | 7 S2 cm
  // 8..11 U0..U3 | 12 S4 cm | 13 V0 | 14 V1 | 15 A | 16..23 XT (16 MB)

  u16* XT = buf(16);
  CvtJobs cv{};
  cv.j[0] = { gs,              buf(0), buf(1) };
  cv.j[1] = { weight + 1 * MB, buf(2), nullptr };
  cv.j[2] = { weight + 3 * MB, buf(3), nullptr };
  cv.j[3] = { weight + 5 * MB, buf(4), nullptr };
  cv.j[4] = { weight + 7 * MB, buf(5), nullptr };
  prep_kernel<<<dim3(5120 + 2048), 256, 0, stream>>>(cv, nodes, XT);

  // L1: S2 = S*S ; U_j = W_{2j}(acc-preload) + W_{2j+1}*S
  // 64x128 tiles, grid 640 = 2.5 blocks/CU, LDS 48KB
  GemmJobs g1{};
  g1.j[0] = { buf(0), buf(1), nullptr,         nullptr, buf(6),  buf(7)  };
  g1.j[1] = { buf(2), buf(1), weight + 0 * MB, nullptr, buf(8),  nullptr };
  g1.j[2] = { buf(3), buf(1), weight + 2 * MB, nullptr, buf(9),  nullptr };
  g1.j[3] = { buf(4), buf(1), weight + 4 * MB, nullptr, buf(10), nullptr };
  g1.j[4] = { buf(5), buf(1), weight + 6 * MB, nullptr, buf(11), nullptr };
  gemm_f16<64, 128, 2, 2><<<dim3(16, 8, 5), 256, 0, stream>>>(g1);

  // L2: S4 = S2*S2 (cm) ; V0 = U0 + U1*S2 ; V1 = U2 + U3*S2
  // 64x64 tiles, grid 768 = 3 blocks/CU, LDS 32KB
  GemmJobs g2{};
  g2.j[0] = { buf(6),  buf(7), nullptr, nullptr, nullptr, buf(12) };
  g2.j[1] = { buf(9),  buf(7), nullptr, buf(8),  buf(13), nullptr };
  g2.j[2] = { buf(11), buf(7), nullptr, buf(10), buf(14), nullptr };
  gemm_f16<64, 64, 2, 2><<<dim3(16, 16, 3), 256, 0, stream>>>(g2);

  // L3: A = V0(fp16 acc-preload) + V1*S4 -- direct write
  GemmJobs g3{};
  g3.j[0] = { buf(14), buf(12), nullptr, buf(13), buf(15), nullptr };
  gemm_f16<64, 64, 2, 2><<<dim3(16, 16, 1), 256, 0, stream>>>(g3);

  apply_gemm<<<dim3(64, 8), 256, 0, stream>>>(buf(15), XT, out);
}